// Round 10
// baseline (158.022 us; speedup 1.0000x reference)
//
#include <hip/hip_runtime.h>

#define NEARZERO 1e-5f
#define RLEN 15
#define LOG2E 1.4426950408889634f

struct __attribute__((packed, aligned(4))) F3 { float x, y, z; };
static __device__ __forceinline__ F3 ld3f(const float* p) {
    return *reinterpret_cast<const F3*>(p);   // dwordx3 load, no overread
}

struct Par { float FC, invFC, invLPFC, K1, K2, PERC, UZL, TT, CFMAX, CFRC, CWH, C; };

static __device__ __forceinline__ void load_par(const float* sp, Par& pr,
                                                float& rout_a, float& rout_b) {
    pr.FC    = fmaf(sp[0], 950.0f, 50.0f);
    pr.K1    = fmaf(sp[1], 0.49f, 0.01f);
    pr.K2    = fmaf(sp[2], 0.199f, 0.001f);
    const float parLP = fmaf(sp[3], 0.8f, 0.2f);
    pr.PERC  = sp[4] * 10.0f;
    pr.UZL   = sp[5] * 100.0f;
    pr.TT    = fmaf(sp[6], 5.0f, -2.5f);
    pr.CFMAX = fmaf(sp[7], 9.5f, 0.5f);
    pr.CFRC  = (sp[8] * 0.1f) * pr.CFMAX;
    pr.CWH   = sp[9] * 0.2f;
    pr.C     = sp[10];
    rout_a   = sp[13] * 2.9f;
    rout_b   = sp[14] * 6.5f;
    pr.invFC   = 1.0f / pr.FC;
    pr.invLPFC = 1.0f / (parLP * pr.FC);
}

static __device__ __forceinline__ void make_w(float rout_a, float rout_b, float (&w)[RLEN]) {
    // gamma FIR; Gamma(aa)*theta^aa cancels in normalization
    const float aa    = fmaxf(rout_a, 0.0f) + 0.1f;
    const float theta = fmaxf(rout_b, 0.0f) + 0.5f;
    const float am1   = aa - 1.0f;
    const float nitl2 = -LOG2E / theta;
    float wsum = 0.0f;
#pragma unroll
    for (int k = 0; k < RLEN; ++k) {
        const float tk = (float)k + 0.5f;
        w[k] = exp2f(am1 * __log2f(tk) + tk * nitl2);
        wsum += w[k];
    }
    const float winv = 1.0f / wsum;
#pragma unroll
    for (int k = 0; k < RLEN; ++k) w[k] *= winv;
}

// Two independent cells, hand-interleaved so in-order issue overlaps the chains.
template<int PH>
__device__ __forceinline__ void one_step2(
    const F3& fA, const F3& dA, const F3& fB, const F3& dB,
    const Par& pA, const Par& pB,
    float& SPa, float& MWa, float& SMa, float& SUa, float& SLa,
    float& SPb, float& MWb, float& SMb, float& SUb, float& SLb,
    float (&accA)[RLEN], float (&accB)[RLEN],
    const float (&wA)[RLEN], const float (&wB)[RLEN],
    float& qrA, float& qrB)
{
    const float beA = fmaf(dA.x, 5.0f, 1.0f);   const float beB = fmaf(dB.x, 5.0f, 1.0f);
    const float k0A = fmaf(dA.y, 0.85f, 0.05f); const float k0B = fmaf(dB.y, 0.85f, 0.05f);
    const float bEA = fmaf(dA.z, 4.7f, 0.3f);   const float bEB = fmaf(dB.z, 4.7f, 0.3f);

    const float dTA = fA.y - pA.TT;             const float dTB = fB.y - pB.TT;
    const float rnA = (dTA >= 0.0f) ? fA.x : 0.0f;
    const float rnB = (dTB >= 0.0f) ? fB.x : 0.0f;
    float spA = SPa + (fA.x - rnA);             float spB = SPb + (fB.x - rnB);
    const float mlA = __builtin_amdgcn_fmed3f(pA.CFMAX * dTA, 0.0f, spA);
    const float mlB = __builtin_amdgcn_fmed3f(pB.CFMAX * dTB, 0.0f, spB);
    float mwA = MWa + mlA;                      float mwB = MWb + mlB;
    spA -= mlA;                                 spB -= mlB;
    const float rfA = __builtin_amdgcn_fmed3f(pA.CFRC * (0.0f - dTA), 0.0f, mwA);
    const float rfB = __builtin_amdgcn_fmed3f(pB.CFRC * (0.0f - dTB), 0.0f, mwB);
    spA += rfA;                                 spB += rfB;
    mwA -= rfA;                                 mwB -= rfB;
    const float tsA = fmaxf(fmaf(-pA.CWH, spA, mwA), 0.0f);
    const float tsB = fmaxf(fmaf(-pB.CWH, spB, mwB), 0.0f);
    mwA -= tsA;                                 mwB -= tsB;
    SPa = spA; MWa = mwA;                       SPb = spB; MWb = mwB;

    float smA = SMa;                            float smB = SMb;
    const float swA = fminf(exp2f(beA * __log2f(smA * pA.invFC)), 1.0f);
    const float swB = fminf(exp2f(beB * __log2f(smB * pB.invFC)), 1.0f);
    const float rtA = rnA + tsA;                const float rtB = rnB + tsB;
    const float rcA = rtA * swA;                const float rcB = rtB * swB;
    smA += rtA - rcA;                           smB += rtB - rcB;
    const float exA = fmaxf(smA - pA.FC, 0.0f); const float exB = fmaxf(smB - pB.FC, 0.0f);
    smA -= exA;                                 smB -= exB;
    const float efA = fminf(exp2f(bEA * __log2f(smA * pA.invLPFC)), 1.0f);
    const float efB = fminf(exp2f(bEB * __log2f(smB * pB.invLPFC)), 1.0f);
    const float etA = fminf(smA, fA.z * efA);   const float etB = fminf(smB, fB.z * efB);
    smA = fmaxf(smA - etA, NEARZERO);           smB = fmaxf(smB - etB, NEARZERO);
    float slA = SLa;                            float slB = SLb;
    const float cpA = pA.C * slA * (1.0f - fminf(smA * pA.invFC, 1.0f));
    const float cpB = pB.C * slB * (1.0f - fminf(smB * pB.invFC, 1.0f));
    smA = fmaxf(smA + cpA, NEARZERO);           smB = fmaxf(smB + cpB, NEARZERO);
    slA = fmaxf(slA - cpA, NEARZERO);           slB = fmaxf(slB - cpB, NEARZERO);
    SMa = smA;                                  SMb = smB;

    float suA = SUa + rcA + exA;                float suB = SUb + rcB + exB;
    const float pcA = fminf(suA, pA.PERC);      const float pcB = fminf(suB, pB.PERC);
    suA -= pcA;                                 suB -= pcB;
    const float q0A = k0A * fmaxf(suA - pA.UZL, 0.0f);
    const float q0B = k0B * fmaxf(suB - pB.UZL, 0.0f);
    suA -= q0A;                                 suB -= q0B;
    const float q1A = pA.K1 * suA;              const float q1B = pB.K1 * suB;
    SUa = suA - q1A;                            SUb = suB - q1B;
    slA += pcA;                                 slB += pcB;
    const float q2A = pA.K2 * slA;              const float q2B = pB.K2 * slB;
    SLa = slA - q2A;                            SLb = slB - q2B;
    const float QA = q0A + q1A + q2A;           const float QB = q0B + q1B + q2B;

    // rotating-accumulator FIR (PH compile-time)
    qrA = fmaf(wA[0], QA, accA[PH]);            qrB = fmaf(wB[0], QB, accB[PH]);
    accA[PH] = 0.0f;                            accB[PH] = 0.0f;
#pragma unroll
    for (int k = 1; k < RLEN; ++k) {
        const int j = (PH + k) % RLEN;          // compile-time
        accA[j] = fmaf(wA[k], QA, accA[j]);
        accB[j] = fmaf(wB[k], QB, accB[j]);
    }
}

__global__ __launch_bounds__(64, 1) __attribute__((amdgpu_waves_per_eu(1, 1)))
void hbv_kernel(const float* __restrict__ forcing,   // (365,G,3)
                const float* __restrict__ dynr,      // (365,G,3)
                const float* __restrict__ statr,     // (G,15)
                float* __restrict__ out,             // (365,G)
                int G, int half)
{
    const int lane = threadIdx.x;
    const int g   = blockIdx.x * 64 + lane;
    const int gA  = (g < half) ? g : (half - 1);           // clamp; store guarded
    const int gBi = half + g;
    const int gB  = (gBi < G) ? gBi : (G - 1);
    const bool guardA = (g < half);
    const bool guardB = (gBi < G);

    // ---- per-cell params + FIR weights ----
    Par prA, prB; float raA, rbA, raB, rbB;
    load_par(statr + (size_t)gA * 15, prA, raA, rbA);
    load_par(statr + (size_t)gB * 15, prB, raB, rbB);
    float wA[RLEN], wB[RLEN];
    make_w(raA, rbA, wA);
    make_w(raB, rbB, wB);

    // ---- state ----
    float SPa = 0.001f, MWa = 0.001f, SMa = 0.001f, SUa = 0.001f, SLa = 0.001f;
    float SPb = 0.001f, MWb = 0.001f, SMb = 0.001f, SUb = 0.001f, SLb = 0.001f;
    float accA[RLEN], accB[RLEN];
#pragma unroll
    for (int k = 0; k < RLEN; ++k) { accA[k] = 0.0f; accB[k] = 0.0f; }

    const size_t sT = (size_t)G * 3;
    const float* pFA = forcing + (size_t)gA * 3;
    const float* pDA = dynr    + (size_t)gA * 3;
    const float* pFB = forcing + (size_t)gB * 3;
    const float* pDB = dynr    + (size_t)gB * 3;

    // ---- depth-3 register ring (3 | 15 -> constexpr slot = phase % 3).
    //      Consume slot S at step t, then overwrite with row t+3: load->use
    //      distance = 3 full steps (~1000+ cyc) with only 36 buffer VGPRs. ----
    F3 bFA[3], bDA[3], bFB[3], bDB[3];
    bFA[0] = ld3f(pFA);          bDA[0] = ld3f(pDA);
    bFB[0] = ld3f(pFB);          bDB[0] = ld3f(pDB);
    bFA[1] = ld3f(pFA + sT);     bDA[1] = ld3f(pDA + sT);
    bFB[1] = ld3f(pFB + sT);     bDB[1] = ld3f(pDB + sT);
    bFA[2] = ld3f(pFA + 2 * sT); bDA[2] = ld3f(pDA + 2 * sT);
    bFB[2] = ld3f(pFB + 2 * sT); bDB[2] = ld3f(pDB + 2 * sT);

    // running pointers at row t+3
    const float* rFA = pFA + 3 * sT;
    const float* rDA = pDA + 3 * sT;
    const float* rFB = pFB + 3 * sT;
    const float* rDB = pDB + 3 * sT;

    float* outp = out + g;

    // Loads are textually AFTER the compute (WAR on the slot) but inside the
    // same sched region; the scheduler hoists them to just after the last
    // slot read. sched_barrier(0) pins them to this step (anti-sink).
#define STEP(PH, FA_, DA_, FB_, DB_) do { \
    constexpr int P_ = (PH) % RLEN; \
    constexpr int S_ = P_ % 3; \
    float qa_, qb_; \
    one_step2<P_>(bFA[S_], bDA[S_], bFB[S_], bDB[S_], prA, prB, \
                  SPa, MWa, SMa, SUa, SLa, SPb, MWb, SMb, SUb, SLb, \
                  accA, accB, wA, wB, qa_, qb_); \
    bFA[S_] = ld3f(FA_); bDA[S_] = ld3f(DA_); \
    bFB[S_] = ld3f(FB_); bDB[S_] = ld3f(DB_); \
    __builtin_amdgcn_sched_barrier(0); \
    if (guardA) __builtin_nontemporal_store(qa_, outp); \
    if (guardB) __builtin_nontemporal_store(qb_, outp + half); \
    outp += G; \
} while (0)

#define STEPADV(PH) do { \
    STEP(PH, rFA, rDA, rFB, rDB); \
    rFA += sT; rDA += sT; rFB += sT; rDB += sT; \
} while (0)

    // ---- main: t = 0..359 (24 x 15); loads rows 3..362, all real ----
    for (int i = 0; i < 24; ++i) {
        STEPADV(0);  STEPADV(1);  STEPADV(2);  STEPADV(3);  STEPADV(4);
        STEPADV(5);  STEPADV(6);  STEPADV(7);  STEPADV(8);  STEPADV(9);
        STEPADV(10); STEPADV(11); STEPADV(12); STEPADV(13); STEPADV(14);
    }
    // ---- tail: t = 360..364 (phases 0..4); row = min(t+3,364); rows 363,364
    //      are real and consumed at t=363,364; clamped slots never consumed ----
#define TR(T) ((((T) + 3) <= 364) ? ((T) + 3) : 364)
    STEP(0, pFA + (size_t)TR(360) * sT, pDA + (size_t)TR(360) * sT,
            pFB + (size_t)TR(360) * sT, pDB + (size_t)TR(360) * sT);
    STEP(1, pFA + (size_t)TR(361) * sT, pDA + (size_t)TR(361) * sT,
            pFB + (size_t)TR(361) * sT, pDB + (size_t)TR(361) * sT);
    STEP(2, pFA + (size_t)TR(362) * sT, pDA + (size_t)TR(362) * sT,
            pFB + (size_t)TR(362) * sT, pDB + (size_t)TR(362) * sT);
    STEP(3, pFA + (size_t)TR(363) * sT, pDA + (size_t)TR(363) * sT,
            pFB + (size_t)TR(363) * sT, pDB + (size_t)TR(363) * sT);
    STEP(4, pFA + (size_t)TR(364) * sT, pDA + (size_t)TR(364) * sT,
            pFB + (size_t)TR(364) * sT, pDB + (size_t)TR(364) * sT);
#undef TR
#undef STEPADV
#undef STEP
}

extern "C" void kernel_launch(void* const* d_in, const int* in_sizes, int n_in,
                              void* d_out, int out_size, void* d_ws, size_t ws_size,
                              hipStream_t stream) {
    const float* forcing = (const float*)d_in[0];
    const float* dynr    = (const float*)d_in[1];
    const float* statr   = (const float*)d_in[2];
    float* out = (float*)d_out;

    const int G    = in_sizes[2] / 15;       // static_raw (G,15); T fixed at 365
    const int half = (G + 1) / 2;            // cell A: [0,half), cell B: [half,G)
    const int block = 64;
    const int grid  = (half + block - 1) / block;
    hbv_kernel<<<grid, block, 0, stream>>>(forcing, dynr, statr, out, G, half);
}

// Round 11
// 114.096 us; speedup vs baseline: 1.3850x; 1.3850x over previous
//
#include <hip/hip_runtime.h>

#define NEARZERO 1e-5f
#define RLEN 15
#define LOG2E 1.4426950408889634f

struct __attribute__((packed, aligned(4))) F3 { float x, y, z; };
static __device__ __forceinline__ F3 ld3f(const float* p) {
    return *reinterpret_cast<const F3*>(p);   // dwordx3 load, no overread
}

struct Par { float FC, invFC, invLPFC, K1, K2, PERC, UZL, TT, CFMAX, CFRC, CWH, C; };

template<int PH>
__device__ __forceinline__ float one_step(
    const F3& f, const F3& d3, const Par& pr,
    float& SNOWPACK, float& MELTWATER, float& SM, float& SUZ, float& SLZ,
    float (&acc)[RLEN], const float (&w)[RLEN])
{
    const float pBETA   = fmaf(d3.x, 5.0f, 1.0f);
    const float pK0     = fmaf(d3.y, 0.85f, 0.05f);
    const float pBETAET = fmaf(d3.z, 4.7f, 0.3f);

    const float d    = f.y - pr.TT;
    const float RAIN = (d >= 0.0f) ? f.x : 0.0f;
    SNOWPACK += f.x - RAIN;
    const float melt = __builtin_amdgcn_fmed3f(pr.CFMAX * d, 0.0f, SNOWPACK);
    MELTWATER += melt;
    SNOWPACK  -= melt;
    const float refr = __builtin_amdgcn_fmed3f(pr.CFRC * (0.0f - d), 0.0f, MELTWATER);
    SNOWPACK  += refr;
    MELTWATER -= refr;
    const float tosoil = fmaxf(fmaf(-pr.CWH, SNOWPACK, MELTWATER), 0.0f);
    MELTWATER -= tosoil;

    const float sw = fminf(exp2f(pBETA * __log2f(SM * pr.invFC)), 1.0f);
    const float rt = RAIN + tosoil;
    const float recharge = rt * sw;
    SM = SM + rt - recharge;
    const float excess = fmaxf(SM - pr.FC, 0.0f);
    SM -= excess;
    const float ef = fminf(exp2f(pBETAET * __log2f(SM * pr.invLPFC)), 1.0f);
    const float ETact = fminf(SM, f.z * ef);
    SM = fmaxf(SM - ETact, NEARZERO);
    const float capillary = pr.C * SLZ * (1.0f - fminf(SM * pr.invFC, 1.0f));
    SM  = fmaxf(SM + capillary, NEARZERO);
    SLZ = fmaxf(SLZ - capillary, NEARZERO);

    SUZ += recharge + excess;
    const float PERC = fminf(SUZ, pr.PERC);
    SUZ -= PERC;
    const float Q0 = pK0 * fmaxf(SUZ - pr.UZL, 0.0f);
    SUZ -= Q0;
    const float Q1 = pr.K1 * SUZ;
    SUZ -= Q1;
    SLZ += PERC;
    const float Q2 = pr.K2 * SLZ;
    SLZ -= Q2;
    const float Qsim = Q0 + Q1 + Q2;

    // rotating-accumulator FIR: out[t] = acc[t%15] + w0*Q[t].
    // These 15 FMAs are off the serial spine; the 0x7 sched_barrier lets them
    // slide into the NEXT step's chain stalls.
    const float qr = fmaf(w[0], Qsim, acc[PH]);
    acc[PH] = 0.0f;
#pragma unroll
    for (int k = 1; k < RLEN; ++k) {
        const int j = (PH + k) % RLEN;      // compile-time
        acc[j] = fmaf(w[k], Qsim, acc[j]);
    }
    return qr;
}

__global__ __launch_bounds__(64, 1)
void hbv_kernel(const float* __restrict__ forcing,   // (365,G,3)
                const float* __restrict__ dynr,      // (365,G,3)
                const float* __restrict__ statr,     // (G,15)
                float* __restrict__ out,             // (365,G)
                int G)
{
    const int lane = threadIdx.x;
    const int g  = blockIdx.x * 64 + lane;
    const int gc = (g < G) ? g : (G - 1);          // clamp for loads; store guarded
    const bool guard = (g < G);

    // ---- static parameters ----
    const float* sp = statr + (size_t)gc * 15;
    Par pr;
    pr.FC    = fmaf(sp[0], 950.0f, 50.0f);
    pr.K1    = fmaf(sp[1], 0.49f, 0.01f);
    pr.K2    = fmaf(sp[2], 0.199f, 0.001f);
    const float parLP = fmaf(sp[3], 0.8f, 0.2f);
    pr.PERC  = sp[4] * 10.0f;
    pr.UZL   = sp[5] * 100.0f;
    pr.TT    = fmaf(sp[6], 5.0f, -2.5f);
    pr.CFMAX = fmaf(sp[7], 9.5f, 0.5f);
    pr.CFRC  = (sp[8] * 0.1f) * pr.CFMAX;
    pr.CWH   = sp[9] * 0.2f;
    pr.C     = sp[10];
    const float rout_a = sp[13] * 2.9f;
    const float rout_b = sp[14] * 6.5f;
    pr.invFC   = 1.0f / pr.FC;
    pr.invLPFC = 1.0f / (parLP * pr.FC);

    // ---- routing weights (Gamma(aa)*theta^aa cancels in normalization) ----
    const float aa    = fmaxf(rout_a, 0.0f) + 0.1f;
    const float theta = fmaxf(rout_b, 0.0f) + 0.5f;
    const float am1   = aa - 1.0f;
    const float nitl2 = -LOG2E / theta;
    float w[RLEN];
    float wsum = 0.0f;
#pragma unroll
    for (int k = 0; k < RLEN; ++k) {
        const float tk = (float)k + 0.5f;
        w[k] = exp2f(am1 * __log2f(tk) + tk * nitl2);
        wsum += w[k];
    }
    const float winv = 1.0f / wsum;
#pragma unroll
    for (int k = 0; k < RLEN; ++k) w[k] *= winv;

    // ---- state ----
    float SP_ = 0.001f, MW = 0.001f, SM = 0.001f, SUZ = 0.001f, SLZ = 0.001f;
    float acc[RLEN];
#pragma unroll
    for (int k = 0; k < RLEN; ++k) acc[k] = 0.0f;

    const size_t sT = (size_t)G * 3;
    const float* pF = forcing + (size_t)gc * 3;
    const float* pD = dynr    + (size_t)gc * 3;

    // ---- depth-3 pure-register ring (3 | 15 -> slot = phase % 3, constexpr).
    //      Consume slot at step t, then overwrite with row t+3: load->use
    //      distance = ~3 steps (>=900 cyc) at only 18 buffer VGPRs. ----
    F3 bF[3], bD[3];
    bF[0] = ld3f(pF);          bD[0] = ld3f(pD);
    bF[1] = ld3f(pF + sT);     bD[1] = ld3f(pD + sT);
    bF[2] = ld3f(pF + 2 * sT); bD[2] = ld3f(pD + 2 * sT);

    const float* rF = pF + 3 * sT;     // running pointer at row t+3
    const float* rD = pD + 3 * sT;
    float* outp = out + g;

    // sched_barrier(0x7): ALU/VALU/SALU may cross (cross-step chain overlap),
    // VMEM/DS may NOT (loads stay pinned to their step - no sinking).
#define STEP(PH, FP, DP) do { \
    constexpr int P_ = (PH) % RLEN; \
    constexpr int S_ = P_ % 3; \
    const float qr_ = one_step<P_>(bF[S_], bD[S_], pr, \
                                   SP_, MW, SM, SUZ, SLZ, acc, w); \
    bF[S_] = ld3f(FP); bD[S_] = ld3f(DP); \
    __builtin_amdgcn_sched_barrier(0x7); \
    if (guard) __builtin_nontemporal_store(qr_, outp); \
    outp += G; \
} while (0)

#define STEPADV(PH) do { \
    STEP(PH, rF, rD); \
    rF += sT; rD += sT; \
} while (0)

    // ---- main: t = 0..359 (24 x 15); loads rows 3..362, all real ----
    for (int i = 0; i < 24; ++i) {
        STEPADV(0);  STEPADV(1);  STEPADV(2);  STEPADV(3);  STEPADV(4);
        STEPADV(5);  STEPADV(6);  STEPADV(7);  STEPADV(8);  STEPADV(9);
        STEPADV(10); STEPADV(11); STEPADV(12); STEPADV(13); STEPADV(14);
    }
    // ---- tail: t = 360..364 (phases 0..4); row = min(t+3,364);
    //      clamped duplicate rows land in slots that are never consumed ----
#define TR(T) ((((T) + 3) <= 364) ? ((T) + 3) : 364)
    STEP(0, pF + (size_t)TR(360) * sT, pD + (size_t)TR(360) * sT);
    STEP(1, pF + (size_t)TR(361) * sT, pD + (size_t)TR(361) * sT);
    STEP(2, pF + (size_t)TR(362) * sT, pD + (size_t)TR(362) * sT);
    STEP(3, pF + (size_t)TR(363) * sT, pD + (size_t)TR(363) * sT);
    STEP(4, pF + (size_t)TR(364) * sT, pD + (size_t)TR(364) * sT);
#undef TR
#undef STEPADV
#undef STEP
}

extern "C" void kernel_launch(void* const* d_in, const int* in_sizes, int n_in,
                              void* d_out, int out_size, void* d_ws, size_t ws_size,
                              hipStream_t stream) {
    const float* forcing = (const float*)d_in[0];
    const float* dynr    = (const float*)d_in[1];
    const float* statr   = (const float*)d_in[2];
    float* out = (float*)d_out;

    const int G = in_sizes[2] / 15;          // static_raw (G,15); T fixed at 365
    const int block = 64;
    const int grid  = (G + block - 1) / block;
    hbv_kernel<<<grid, block, 0, stream>>>(forcing, dynr, statr, out, G);
}

// Round 12
// 103.892 us; speedup vs baseline: 1.5210x; 1.0982x over previous
//
#include <hip/hip_runtime.h>

#define NEARZERO 1e-5f
#define RLEN 15
#define LOG2E 1.4426950408889634f

struct __attribute__((packed, aligned(4))) F3 { float x, y, z; };
static __device__ __forceinline__ F3 ld3f(const float* p) {
    return *reinterpret_cast<const F3*>(p);   // dwordx3 load
}

struct Par { float FC, invFC, invLPFC, K1, K2, PERC, UZL, TT, CFMAX, CFRC, CWH, C; };

// ---- finish step m: zones (upper/lower) + FIR + store; produces cs for soil(m+1) ----
template<int PH>
__device__ __forceinline__ void finish_step(
    const Par& pr, float& SUZ, float& SLZ,
    float rxP, float k0P,
    float (&acc)[RLEN], const float (&w)[RLEN],
    float& cs, float*& outp, int G, bool guard)
{
    SUZ += rxP;                                  // recharge + excess of step m
    const float PERCv = fminf(SUZ, pr.PERC);
    SUZ -= PERCv;
    const float Q0 = k0P * fmaxf(SUZ - pr.UZL, 0.0f);
    SUZ -= Q0;
    const float Q1 = pr.K1 * SUZ;
    SUZ -= Q1;
    SLZ += PERCv;
    const float Q2 = pr.K2 * SLZ;
    SLZ -= Q2;
    const float Qs = Q0 + Q1 + Q2;

    // rotating-accumulator FIR: out[m] = acc[m%15] + w0*Qs
    const float qr = fmaf(w[0], Qs, acc[PH]);
    acc[PH] = 0.0f;
#pragma unroll
    for (int k = 1; k < RLEN; ++k) {
        const int j = (PH + k) % RLEN;           // compile-time
        acc[j] = fmaf(w[k], Qs, acc[j]);
    }
    if (guard) *outp = qr;
    outp += G;
    cs = pr.C * SLZ;                             // off-spine input to soil(m+1)
}

// ---- snow + soil of step t (consumes forcing/dyn of t, cs from finish(t-1)) ----
__device__ __forceinline__ void ab_step(
    const F3& f, const F3& d3, const Par& pr,
    float& SP, float& MW, float& SM, float& SLZ,
    float cs, float& rxP, float& k0P)
{
    const float pBETA   = fmaf(d3.x, 5.0f, 1.0f);
    const float pBETAET = fmaf(d3.z, 4.7f, 0.3f);

    // snow (recurrence: SP,MW only)
    const float dT   = f.y - pr.TT;
    const float RAIN = (dT >= 0.0f) ? f.x : 0.0f;
    SP += f.x - RAIN;
    const float melt = __builtin_amdgcn_fmed3f(pr.CFMAX * dT, 0.0f, SP);
    MW += melt;  SP -= melt;
    const float refr = __builtin_amdgcn_fmed3f(pr.CFRC * (0.0f - dT), 0.0f, MW);
    SP += refr;  MW -= refr;
    const float tosoil = fmaxf(fmaf(-pr.CWH, SP, MW), 0.0f);
    MW -= tosoil;

    // soil (recurrence: SM; SLZ via capillary)
    const float sw = fminf(exp2f(pBETA * __log2f(SM * pr.invFC)), 1.0f);
    const float rt = RAIN + tosoil;
    const float rc = rt * sw;
    SM = fmaf(rt, 1.0f - sw, SM);
    const float ex = fmaxf(SM - pr.FC, 0.0f);
    SM = fminf(SM, pr.FC);                       // == SM - excess
    const float ef = fminf(exp2f(pBETAET * __log2f(SM * pr.invLPFC)), 1.0f);
    SM = fmaxf(SM - f.z * ef, NEARZERO);         // == SM - min(SM, PET*ef), clamped
    const float cap = cs * (1.0f - fminf(SM * pr.invFC, 1.0f));  // cap <= SLZ since C<=1
    SM  = fmaxf(SM + cap, NEARZERO);
    SLZ = fmaxf(SLZ - cap, NEARZERO);

    rxP = rc + ex;                               // handed to finish(t)
    k0P = fmaf(d3.y, 0.85f, 0.05f);              // dyn K0 of step t, used in finish(t)
}

__global__ __launch_bounds__(64, 1)
void hbv_kernel(const float* __restrict__ forcing,   // (365,G,3)
                const float* __restrict__ dynr,      // (365,G,3)
                const float* __restrict__ statr,     // (G,15)
                float* __restrict__ out,             // (365,G)
                int G)
{
    const int lane = threadIdx.x;
    const int g  = blockIdx.x * 64 + lane;
    const int gc = (g < G) ? g : (G - 1);          // clamp for loads; store guarded
    const bool guard = (g < G);

    // ---- static parameters ----
    const float* sp = statr + (size_t)gc * 15;
    Par pr;
    pr.FC    = fmaf(sp[0], 950.0f, 50.0f);
    pr.K1    = fmaf(sp[1], 0.49f, 0.01f);
    pr.K2    = fmaf(sp[2], 0.199f, 0.001f);
    const float parLP = fmaf(sp[3], 0.8f, 0.2f);
    pr.PERC  = sp[4] * 10.0f;
    pr.UZL   = sp[5] * 100.0f;
    pr.TT    = fmaf(sp[6], 5.0f, -2.5f);
    pr.CFMAX = fmaf(sp[7], 9.5f, 0.5f);
    pr.CFRC  = (sp[8] * 0.1f) * pr.CFMAX;
    pr.CWH   = sp[9] * 0.2f;
    pr.C     = sp[10];
    const float rout_a = sp[13] * 2.9f;
    const float rout_b = sp[14] * 6.5f;
    pr.invFC   = 1.0f / pr.FC;
    pr.invLPFC = 1.0f / (parLP * pr.FC);

    // ---- routing weights (Gamma(aa)*theta^aa cancels in normalization) ----
    const float aa    = fmaxf(rout_a, 0.0f) + 0.1f;
    const float theta = fmaxf(rout_b, 0.0f) + 0.5f;
    const float am1   = aa - 1.0f;
    const float nitl2 = -LOG2E / theta;
    float w[RLEN];
    float wsum = 0.0f;
#pragma unroll
    for (int k = 0; k < RLEN; ++k) {
        const float tk = (float)k + 0.5f;
        w[k] = exp2f(am1 * __log2f(tk) + tk * nitl2);
        wsum += w[k];
    }
    const float winv = 1.0f / wsum;
#pragma unroll
    for (int k = 0; k < RLEN; ++k) w[k] *= winv;

    // ---- state ----
    float SP_ = 0.001f, MW = 0.001f, SM = 0.001f, SUZ = 0.001f, SLZ = 0.001f;
    float acc[RLEN];
#pragma unroll
    for (int k = 0; k < RLEN; ++k) acc[k] = 0.0f;
    float rxP = 0.0f, k0P = 0.0f, cs = 0.0f;

    const size_t sT = (size_t)G * 3;
    const float* pF = forcing + (size_t)gc * 3;
    const float* pD = dynr    + (size_t)gc * 3;
    float* outp = out + g;

    // ---- depth-5 register ring (5 | 15 -> slot = t % 5, constexpr) ----
    F3 bF[5], bD[5];
    bF[0] = ld3f(pF);          bD[0] = ld3f(pD);
    bF[1] = ld3f(pF + sT);     bD[1] = ld3f(pD + sT);
    bF[2] = ld3f(pF + 2 * sT); bD[2] = ld3f(pD + 2 * sT);
    bF[3] = ld3f(pF + 3 * sT); bD[3] = ld3f(pD + 3 * sT);
    bF[4] = ld3f(pF + 4 * sT); bD[4] = ld3f(pD + 4 * sT);

    const float* rF = pF + 5 * sT;     // next row to stage
    const float* rD = pD + 5 * sT;

    // ---- prologue: snow+soil of t=0 (capillary uses initial SLZ) ----
    cs = pr.C * SLZ;
    {
        const F3 f_ = bF[0], d_ = bD[0];
        bF[0] = ld3f(rF); bD[0] = ld3f(rD);        // stage row 5 -> slot 0
        rF += sT; rD += sT;
        __builtin_amdgcn_sched_barrier(0x7);       // VMEM pinned; VALU may cross
        ab_step(f_, d_, pr, SP_, MW, SM, SLZ, cs, rxP, k0P);
    }

    // Iteration m: finish(m) [zones+FIR+store]  ||  snow+soil(m+1).
    // finish(m) is independent of snow(m+1) -> scheduler overlaps the chains.
#define ITER(MM, FP, DP) do { \
    constexpr int PH_ = (MM) % RLEN; \
    constexpr int S_  = ((MM) + 1) % 5; \
    finish_step<PH_>(pr, SUZ, SLZ, rxP, k0P, acc, w, cs, outp, G, guard); \
    const F3 f_ = bF[S_], d_ = bD[S_]; \
    bF[S_] = ld3f(FP); bD[S_] = ld3f(DP); \
    __builtin_amdgcn_sched_barrier(0x7); \
    ab_step(f_, d_, pr, SP_, MW, SM, SLZ, cs, rxP, k0P); \
} while (0)

#define ITERADV(MM) do { ITER(MM, rF, rD); rF += sT; rD += sT; } while (0)

    // no-load variant (ring already holds the remaining rows)
#define ITER_NL(MM) do { \
    constexpr int PH_ = (MM) % RLEN; \
    constexpr int S_  = ((MM) + 1) % 5; \
    finish_step<PH_>(pr, SUZ, SLZ, rxP, k0P, acc, w, cs, outp, G, guard); \
    const F3 f_ = bF[S_], d_ = bD[S_]; \
    ab_step(f_, d_, pr, SP_, MW, SM, SLZ, cs, rxP, k0P); \
} while (0)

    // ---- main: m = 0..344 (23 x 15); stages rows 6..350, all real ----
    for (int i = 0; i < 23; ++i) {
        ITERADV(0);  ITERADV(1);  ITERADV(2);  ITERADV(3);  ITERADV(4);
        ITERADV(5);  ITERADV(6);  ITERADV(7);  ITERADV(8);  ITERADV(9);
        ITERADV(10); ITERADV(11); ITERADV(12); ITERADV(13); ITERADV(14);
    }
    // ---- penultimate block: m = 345..359; stages rows 351..364 (m=359 re-stages 364,
    //      its slot (t=365) is never consumed) ----
    ITERADV(0);  ITERADV(1);  ITERADV(2);  ITERADV(3);  ITERADV(4);
    ITERADV(5);  ITERADV(6);  ITERADV(7);  ITERADV(8);  ITERADV(9);
    ITERADV(10); ITERADV(11); ITERADV(12); ITERADV(13);
    ITER(14, pF + (size_t)364 * sT, pD + (size_t)364 * sT);   // m=359
    // ---- epilogue: m = 360..363 consume rows 361..364 (already staged) ----
    ITER_NL(0); ITER_NL(1); ITER_NL(2); ITER_NL(3);
    // ---- final: finish(364), phase 364%15 = 4 ----
    finish_step<4>(pr, SUZ, SLZ, rxP, k0P, acc, w, cs, outp, G, guard);
#undef ITER_NL
#undef ITERADV
#undef ITER
}

extern "C" void kernel_launch(void* const* d_in, const int* in_sizes, int n_in,
                              void* d_out, int out_size, void* d_ws, size_t ws_size,
                              hipStream_t stream) {
    const float* forcing = (const float*)d_in[0];
    const float* dynr    = (const float*)d_in[1];
    const float* statr   = (const float*)d_in[2];
    float* out = (float*)d_out;

    const int G = in_sizes[2] / 15;          // static_raw (G,15); T fixed at 365
    const int block = 64;
    const int grid  = (G + block - 1) / block;
    hbv_kernel<<<grid, block, 0, stream>>>(forcing, dynr, statr, out, G);
}

// Round 13
// 99.847 us; speedup vs baseline: 1.5826x; 1.0405x over previous
//
#include <hip/hip_runtime.h>

#define NEARZERO 1e-5f
#define RLEN 15
#define LOG2E 1.4426950408889634f

struct __attribute__((packed, aligned(4))) F3 { float x, y, z; };
static __device__ __forceinline__ F3 ld3f(const float* p) {
    return *reinterpret_cast<const F3*>(p);   // dwordx3 load
}

struct Par { float FC, invFC, invLPFC, K1, K2, PERC, UZL, TT, CFMAX, CFRC, CWH, C; };

// ---- finish step m: zones (upper/lower) + FIR + store; produces cs for soil(m+1) ----
template<int PH>
__device__ __forceinline__ void finish_step(
    const Par& pr, float& SUZ, float& SLZ,
    float rxP, float k0P,
    float (&acc)[RLEN], const float (&w)[RLEN],
    float& cs, float*& outp, int G, bool guard)
{
    SUZ += rxP;                                  // recharge + excess of step m
    const float PERCv = fminf(SUZ, pr.PERC);
    SUZ -= PERCv;
    const float Q0 = k0P * fmaxf(SUZ - pr.UZL, 0.0f);
    SUZ -= Q0;
    const float Q1 = pr.K1 * SUZ;
    SUZ -= Q1;
    SLZ += PERCv;
    const float Q2 = pr.K2 * SLZ;
    SLZ -= Q2;
    const float Qs = Q0 + Q1 + Q2;

    // rotating-accumulator FIR: out[m] = acc[m%15] + w0*Qs
    const float qr = fmaf(w[0], Qs, acc[PH]);
    acc[PH] = 0.0f;
#pragma unroll
    for (int k = 1; k < RLEN; ++k) {
        const int j = (PH + k) % RLEN;           // compile-time
        acc[j] = fmaf(w[k], Qs, acc[j]);
    }
    if (guard) __builtin_nontemporal_store(qr, outp);
    outp += G;
    cs = pr.C * SLZ;                             // off-spine input to soil(m+1)
}

// ---- snow + soil of step t (consumes forcing/dyn of t, cs from finish(t-1)) ----
__device__ __forceinline__ void ab_step(
    const F3& f, const F3& d3, const Par& pr,
    float& SP, float& MW, float& SM, float& SLZ,
    float cs, float& rxP, float& k0P)
{
    const float pBETA   = fmaf(d3.x, 5.0f, 1.0f);
    const float pBETAET = fmaf(d3.z, 4.7f, 0.3f);

    // snow (recurrence: SP,MW only)
    const float dT   = f.y - pr.TT;
    const float RAIN = (dT >= 0.0f) ? f.x : 0.0f;
    SP += f.x - RAIN;
    const float melt = __builtin_amdgcn_fmed3f(pr.CFMAX * dT, 0.0f, SP);
    MW += melt;  SP -= melt;
    const float refr = __builtin_amdgcn_fmed3f(pr.CFRC * (0.0f - dT), 0.0f, MW);
    SP += refr;  MW -= refr;
    const float tosoil = fmaxf(fmaf(-pr.CWH, SP, MW), 0.0f);
    MW -= tosoil;

    // soil (recurrence: SM; SLZ via capillary)
    const float sw = fminf(exp2f(pBETA * __log2f(SM * pr.invFC)), 1.0f);
    const float rt = RAIN + tosoil;
    const float rc = rt * sw;
    SM = fmaf(rt, 1.0f - sw, SM);
    const float ex = fmaxf(SM - pr.FC, 0.0f);
    SM = fminf(SM, pr.FC);                       // == SM - excess
    const float ef = fminf(exp2f(pBETAET * __log2f(SM * pr.invLPFC)), 1.0f);
    SM = fmaxf(SM - f.z * ef, NEARZERO);         // == SM - min(SM, PET*ef), clamped
    const float cap = cs * (1.0f - fminf(SM * pr.invFC, 1.0f));  // cap <= SLZ since C<=1
    SM  = fmaxf(SM + cap, NEARZERO);
    SLZ = fmaxf(SLZ - cap, NEARZERO);

    rxP = rc + ex;                               // handed to finish(t)
    k0P = fmaf(d3.y, 0.85f, 0.05f);              // dyn K0 of step t, used in finish(t)
}

__global__ __launch_bounds__(256, 1)
void hbv_kernel(const float* __restrict__ forcing,   // (365,G,3)
                const float* __restrict__ dynr,      // (365,G,3)
                const float* __restrict__ statr,     // (G,15)
                float* __restrict__ out,             // (365,G)
                int G)
{
    const int g  = blockIdx.x * 256 + threadIdx.x;
    const int gc = (g < G) ? g : (G - 1);          // clamp for loads; store guarded
    const bool guard = (g < G);

    // ---- static parameters ----
    const float* sp = statr + (size_t)gc * 15;
    Par pr;
    pr.FC    = fmaf(sp[0], 950.0f, 50.0f);
    pr.K1    = fmaf(sp[1], 0.49f, 0.01f);
    pr.K2    = fmaf(sp[2], 0.199f, 0.001f);
    const float parLP = fmaf(sp[3], 0.8f, 0.2f);
    pr.PERC  = sp[4] * 10.0f;
    pr.UZL   = sp[5] * 100.0f;
    pr.TT    = fmaf(sp[6], 5.0f, -2.5f);
    pr.CFMAX = fmaf(sp[7], 9.5f, 0.5f);
    pr.CFRC  = (sp[8] * 0.1f) * pr.CFMAX;
    pr.CWH   = sp[9] * 0.2f;
    pr.C     = sp[10];
    const float rout_a = sp[13] * 2.9f;
    const float rout_b = sp[14] * 6.5f;
    pr.invFC   = 1.0f / pr.FC;
    pr.invLPFC = 1.0f / (parLP * pr.FC);

    // ---- routing weights (Gamma(aa)*theta^aa cancels in normalization) ----
    const float aa    = fmaxf(rout_a, 0.0f) + 0.1f;
    const float theta = fmaxf(rout_b, 0.0f) + 0.5f;
    const float am1   = aa - 1.0f;
    const float nitl2 = -LOG2E / theta;
    float w[RLEN];
    float wsum = 0.0f;
#pragma unroll
    for (int k = 0; k < RLEN; ++k) {
        const float tk = (float)k + 0.5f;
        w[k] = exp2f(am1 * __log2f(tk) + tk * nitl2);
        wsum += w[k];
    }
    const float winv = 1.0f / wsum;
#pragma unroll
    for (int k = 0; k < RLEN; ++k) w[k] *= winv;

    // ---- state ----
    float SP_ = 0.001f, MW = 0.001f, SM = 0.001f, SUZ = 0.001f, SLZ = 0.001f;
    float acc[RLEN];
#pragma unroll
    for (int k = 0; k < RLEN; ++k) acc[k] = 0.0f;
    float rxP = 0.0f, k0P = 0.0f, cs = 0.0f;

    const size_t sT = (size_t)G * 3;
    const float* pF = forcing + (size_t)gc * 3;
    const float* pD = dynr    + (size_t)gc * 3;
    float* outp = out + g;

    // ---- depth-5 register ring (5 | 15 -> slot = t % 5, constexpr) ----
    F3 bF[5], bD[5];
    bF[0] = ld3f(pF);          bD[0] = ld3f(pD);
    bF[1] = ld3f(pF + sT);     bD[1] = ld3f(pD + sT);
    bF[2] = ld3f(pF + 2 * sT); bD[2] = ld3f(pD + 2 * sT);
    bF[3] = ld3f(pF + 3 * sT); bD[3] = ld3f(pD + 3 * sT);
    bF[4] = ld3f(pF + 4 * sT); bD[4] = ld3f(pD + 4 * sT);

    const float* rF = pF + 5 * sT;     // next row to stage
    const float* rD = pD + 5 * sT;

    // ---- prologue: snow+soil of t=0 (capillary uses initial SLZ) ----
    cs = pr.C * SLZ;
    {
        const F3 f_ = bF[0], d_ = bD[0];
        bF[0] = ld3f(rF); bD[0] = ld3f(rD);        // stage row 5 -> slot 0
        rF += sT; rD += sT;
        __builtin_amdgcn_sched_barrier(0x7);       // VMEM pinned; VALU may cross
        ab_step(f_, d_, pr, SP_, MW, SM, SLZ, cs, rxP, k0P);
    }

    // Iteration m: finish(m) [zones+FIR+store]  ||  snow+soil(m+1).
    // finish(m) is independent of snow(m+1) -> scheduler overlaps the chains.
#define ITER(MM, FP, DP) do { \
    constexpr int PH_ = (MM) % RLEN; \
    constexpr int S_  = ((MM) + 1) % 5; \
    finish_step<PH_>(pr, SUZ, SLZ, rxP, k0P, acc, w, cs, outp, G, guard); \
    const F3 f_ = bF[S_], d_ = bD[S_]; \
    bF[S_] = ld3f(FP); bD[S_] = ld3f(DP); \
    __builtin_amdgcn_sched_barrier(0x7); \
    ab_step(f_, d_, pr, SP_, MW, SM, SLZ, cs, rxP, k0P); \
} while (0)

#define ITERADV(MM) do { ITER(MM, rF, rD); rF += sT; rD += sT; } while (0)

    // no-load variant (ring already holds the remaining rows)
#define ITER_NL(MM) do { \
    constexpr int PH_ = (MM) % RLEN; \
    constexpr int S_  = ((MM) + 1) % 5; \
    finish_step<PH_>(pr, SUZ, SLZ, rxP, k0P, acc, w, cs, outp, G, guard); \
    const F3 f_ = bF[S_], d_ = bD[S_]; \
    ab_step(f_, d_, pr, SP_, MW, SM, SLZ, cs, rxP, k0P); \
} while (0)

    // ---- main: m = 0..344 (23 x 15); stages rows 6..350, all real ----
    for (int i = 0; i < 23; ++i) {
        ITERADV(0);  ITERADV(1);  ITERADV(2);  ITERADV(3);  ITERADV(4);
        ITERADV(5);  ITERADV(6);  ITERADV(7);  ITERADV(8);  ITERADV(9);
        ITERADV(10); ITERADV(11); ITERADV(12); ITERADV(13); ITERADV(14);
    }
    // ---- penultimate block: m = 345..359; stages rows 351..364 (m=359 re-stages 364,
    //      its slot (t=365) is never consumed) ----
    ITERADV(0);  ITERADV(1);  ITERADV(2);  ITERADV(3);  ITERADV(4);
    ITERADV(5);  ITERADV(6);  ITERADV(7);  ITERADV(8);  ITERADV(9);
    ITERADV(10); ITERADV(11); ITERADV(12); ITERADV(13);
    ITER(14, pF + (size_t)364 * sT, pD + (size_t)364 * sT);   // m=359
    // ---- epilogue: m = 360..363 consume rows 361..364 (already staged) ----
    ITER_NL(0); ITER_NL(1); ITER_NL(2); ITER_NL(3);
    // ---- final: finish(364), phase 364%15 = 4 ----
    finish_step<4>(pr, SUZ, SLZ, rxP, k0P, acc, w, cs, outp, G, guard);
#undef ITER_NL
#undef ITERADV
#undef ITER
}

extern "C" void kernel_launch(void* const* d_in, const int* in_sizes, int n_in,
                              void* d_out, int out_size, void* d_ws, size_t ws_size,
                              hipStream_t stream) {
    const float* forcing = (const float*)d_in[0];
    const float* dynr    = (const float*)d_in[1];
    const float* statr   = (const float*)d_in[2];
    float* out = (float*)d_out;

    const int G = in_sizes[2] / 15;          // static_raw (G,15); T fixed at 365
    // block=256, grid=196 <= 256 CUs: exactly one block per CU (4 waves on
    // 4 SIMDs), NO sequential second round — removes the dispatch tail that
    // was doubling kernel duration (782 blocks = 3.05/CU -> stragglers).
    const int block = 256;
    const int grid  = (G + block - 1) / block;
    hbv_kernel<<<grid, block, 0, stream>>>(forcing, dynr, statr, out, G);
}

// Round 14
// 97.586 us; speedup vs baseline: 1.6193x; 1.0232x over previous
//
#include <hip/hip_runtime.h>

#define NEARZERO 1e-5f
#define RLEN 15
#define LOG2E 1.4426950408889634f

struct __attribute__((packed, aligned(4))) F3 { float x, y, z; };
static __device__ __forceinline__ F3 ldo(const char* base, unsigned voff) {
    return *reinterpret_cast<const F3*>(base + voff);   // saddr + 32-bit voffset form
}

struct Par { float FC, invFC, invLPFC, K1, K2, PERC, UZL, TT, CFMAX, CFRC, CWH, C; };

// ---- prologue-only: snow+soil of t=0 ----
__device__ __forceinline__ void ab_step(
    const F3& f, const F3& d3, const Par& pr,
    float& SP, float& MW, float& SM, float& SLZ,
    float cs, float& rxP, float& k0P)
{
    const float pBETA   = fmaf(d3.x, 5.0f, 1.0f);
    const float pBETAET = fmaf(d3.z, 4.7f, 0.3f);
    const float dT   = f.y - pr.TT;
    const float RAIN = (dT >= 0.0f) ? f.x : 0.0f;
    SP += f.x - RAIN;
    const float melt = __builtin_amdgcn_fmed3f(pr.CFMAX * dT, 0.0f, SP);
    MW += melt;  SP -= melt;
    const float refr = __builtin_amdgcn_fmed3f(pr.CFRC * (0.0f - dT), 0.0f, MW);
    SP += refr;  MW -= refr;
    const float tosoil = fmaxf(fmaf(-pr.CWH, SP, MW), 0.0f);
    MW -= tosoil;
    const float sw = fminf(exp2f(pBETA * __log2f(SM * pr.invFC)), 1.0f);
    const float rt = RAIN + tosoil;
    const float rc = rt * sw;
    SM = fmaf(rt, 1.0f - sw, SM);
    const float ex = fmaxf(SM - pr.FC, 0.0f);
    SM = fminf(SM, pr.FC);
    const float ef = fminf(exp2f(pBETAET * __log2f(SM * pr.invLPFC)), 1.0f);
    SM = fmaxf(SM - f.z * ef, NEARZERO);
    const float cap = cs * (1.0f - fminf(SM * pr.invFC, 1.0f));
    SM  = fmaxf(SM + cap, NEARZERO);
    SLZ = fmaxf(SLZ - cap, NEARZERO);
    rxP = rc + ex;
    k0P = fmaf(d3.y, 0.85f, 0.05f);
}

// ---- fused: finish(m) [zones+FIR+store] hand-interleaved with ab(m+1),
//      ordered so every transcendental's latency is covered by independent work ----
template<int PH>
__device__ __forceinline__ void fused_iter(
    const F3 f, const F3 d3, const Par& pr,
    float& SP, float& MW, float& SM, float& SUZ, float& SLZ,
    float& rxP, float& k0P,
    float (&acc)[RLEN], const float (&w)[RLEN],
    float* outp, bool guard)
{
    // spine head of ab(m+1): SM(m) is ready NOW -> start trans #1 first
    const float t1 = __log2f(SM * pr.invFC);
    // snow of m+1 (independent; hides t1 latency)
    const float dT   = f.y - pr.TT;
    const float RAIN = (dT >= 0.0f) ? f.x : 0.0f;
    SP += f.x - RAIN;
    const float melt = __builtin_amdgcn_fmed3f(pr.CFMAX * dT, 0.0f, SP);
    MW += melt;  SP -= melt;
    const float refr = __builtin_amdgcn_fmed3f(pr.CFRC * (0.0f - dT), 0.0f, MW);
    SP += refr;  MW -= refr;
    const float tosoil = fmaxf(fmaf(-pr.CWH, SP, MW), 0.0f);
    MW -= tosoil;
    // finish(m) upper zone (independent)
    SUZ += rxP;
    const float PERCv = fminf(SUZ, pr.PERC);
    SUZ -= PERCv;
    const float Q0 = k0P * fmaxf(SUZ - pr.UZL, 0.0f);
    SUZ -= Q0;
    const float Q1 = pr.K1 * SUZ;
    SUZ -= Q1;
    // soil wetness (t1 long ready) -> trans #2; its latency hides under lower zone
    const float pBETA = fmaf(d3.x, 5.0f, 1.0f);
    const float sw = fminf(exp2f(pBETA * t1), 1.0f);
    const float rt = RAIN + tosoil;
    // finish(m) lower zone + Qs (independent of sw)
    SLZ += PERCv;
    const float Q2 = pr.K2 * SLZ;
    SLZ -= Q2;
    const float Qs = Q0 + Q1 + Q2;
    const float cs = pr.C * SLZ;                 // zones(m)-final SLZ -> capillary(m+1)
    // soil recharge/excess (sw ready)
    const float rc = rt * sw;
    SM = fmaf(rt, 1.0f - sw, SM);
    const float ex = fmaxf(SM - pr.FC, 0.0f);
    SM = fminf(SM, pr.FC);
    const float t2 = __log2f(SM * pr.invLPFC);   // trans #3; hidden by FIR below
    // FIR of m + store (15 independent FMAs fill t2's latency)
    const float qr = fmaf(w[0], Qs, acc[PH]);
    acc[PH] = 0.0f;
#pragma unroll
    for (int k = 1; k < RLEN; ++k) {
        const int j = (PH + k) % RLEN;           // compile-time
        acc[j] = fmaf(w[k], Qs, acc[j]);
    }
    if (guard) __builtin_nontemporal_store(qr, outp);
    // soil tail (trans #4 latency partially hidden by cs/cap prep)
    const float pBETAET = fmaf(d3.z, 4.7f, 0.3f);
    const float ef = fminf(exp2f(pBETAET * t2), 1.0f);
    SM = fmaxf(SM - f.z * ef, NEARZERO);
    const float cap = cs * (1.0f - fminf(SM * pr.invFC, 1.0f));   // cap <= SLZ (C<=1)
    SM  = fmaxf(SM + cap, NEARZERO);
    SLZ = fmaxf(SLZ - cap, NEARZERO);
    rxP = rc + ex;
    k0P = fmaf(d3.y, 0.85f, 0.05f);
}

// ---- final step's zones+FIR+store only ----
template<int PH>
__device__ __forceinline__ void finish_step(
    const Par& pr, float& SUZ, float& SLZ, float rxP, float k0P,
    float (&acc)[RLEN], const float (&w)[RLEN], float* outp, bool guard)
{
    SUZ += rxP;
    const float PERCv = fminf(SUZ, pr.PERC);
    SUZ -= PERCv;
    const float Q0 = k0P * fmaxf(SUZ - pr.UZL, 0.0f);
    SUZ -= Q0;
    const float Q1 = pr.K1 * SUZ;
    SUZ -= Q1;
    SLZ += PERCv;
    const float Q2 = pr.K2 * SLZ;
    SLZ -= Q2;
    const float Qs = Q0 + Q1 + Q2;
    const float qr = fmaf(w[0], Qs, acc[PH]);
    if (guard) __builtin_nontemporal_store(qr, outp);
}

__global__ __launch_bounds__(256, 1)
void hbv_kernel(const float* __restrict__ forcing,   // (365,G,3)
                const float* __restrict__ dynr,      // (365,G,3)
                const float* __restrict__ statr,     // (G,15)
                float* __restrict__ out,             // (365,G)
                int G)
{
    const int g  = blockIdx.x * 256 + threadIdx.x;
    const int gc = (g < G) ? g : (G - 1);          // clamp for loads; store guarded
    const bool guard = (g < G);

    // ---- static parameters ----
    const float* sp = statr + (size_t)gc * 15;
    Par pr;
    pr.FC    = fmaf(sp[0], 950.0f, 50.0f);
    pr.K1    = fmaf(sp[1], 0.49f, 0.01f);
    pr.K2    = fmaf(sp[2], 0.199f, 0.001f);
    const float parLP = fmaf(sp[3], 0.8f, 0.2f);
    pr.PERC  = sp[4] * 10.0f;
    pr.UZL   = sp[5] * 100.0f;
    pr.TT    = fmaf(sp[6], 5.0f, -2.5f);
    pr.CFMAX = fmaf(sp[7], 9.5f, 0.5f);
    pr.CFRC  = (sp[8] * 0.1f) * pr.CFMAX;
    pr.CWH   = sp[9] * 0.2f;
    pr.C     = sp[10];
    const float rout_a = sp[13] * 2.9f;
    const float rout_b = sp[14] * 6.5f;
    pr.invFC   = 1.0f / pr.FC;
    pr.invLPFC = 1.0f / (parLP * pr.FC);

    // ---- routing weights (Gamma(aa)*theta^aa cancels in normalization) ----
    const float aa    = fmaxf(rout_a, 0.0f) + 0.1f;
    const float theta = fmaxf(rout_b, 0.0f) + 0.5f;
    const float am1   = aa - 1.0f;
    const float nitl2 = -LOG2E / theta;
    float w[RLEN];
    float wsum = 0.0f;
#pragma unroll
    for (int k = 0; k < RLEN; ++k) {
        const float tk = (float)k + 0.5f;
        w[k] = exp2f(am1 * __log2f(tk) + tk * nitl2);
        wsum += w[k];
    }
    const float winv = 1.0f / wsum;
#pragma unroll
    for (int k = 0; k < RLEN; ++k) w[k] *= winv;

    // ---- state ----
    float SP_ = 0.001f, MW = 0.001f, SM = 0.001f, SUZ = 0.001f, SLZ = 0.001f;
    float acc[RLEN];
#pragma unroll
    for (int k = 0; k < RLEN; ++k) acc[k] = 0.0f;
    float rxP = 0.0f, k0P = 0.0f;

    // ---- uniform-base + 32-bit voffset addressing (1 VALU/step/stream) ----
    const char* fbase = (const char*)forcing;
    const char* dbase = (const char*)dynr;
    char*       obase = (char*)out;
    const unsigned G12 = (unsigned)G * 12u;        // bytes per time row (streams)
    const unsigned G4  = (unsigned)G * 4u;         // bytes per time row (out)
    unsigned vRun = (unsigned)gc * 12u;            // row 0, this lane
    unsigned vO   = (unsigned)g  * 4u;             // out row 0 (g; OOB guarded)

    // ---- depth-5 register ring (5 | 15 -> slot = t % 5, constexpr) ----
    F3 bF[5], bD[5];
#pragma unroll
    for (int r = 0; r < 5; ++r) {
        bF[r] = ldo(fbase, vRun); bD[r] = ldo(dbase, vRun);
        vRun += G12;
    }                                               // vRun now at row 5

    // ---- prologue: snow+soil of t=0 (capillary uses initial SLZ) ----
    {
        const float cs0 = pr.C * SLZ;
        const F3 f_ = bF[0], d_ = bD[0];
        bF[0] = ldo(fbase, vRun); bD[0] = ldo(dbase, vRun);   // stage row 5 -> slot 0
        vRun += G12;
        __builtin_amdgcn_sched_barrier(0x7);        // pin VMEM; ALU may cross
        ab_step(f_, d_, pr, SP_, MW, SM, SLZ, cs0, rxP, k0P);
    }

#define ITER(MM, VOFF) do { \
    constexpr int PH_ = (MM) % RLEN; \
    constexpr int S_  = ((MM) + 1) % 5; \
    const F3 f_ = bF[S_], d_ = bD[S_]; \
    bF[S_] = ldo(fbase, (VOFF)); bD[S_] = ldo(dbase, (VOFF)); \
    __builtin_amdgcn_sched_barrier(0x7); \
    fused_iter<PH_>(f_, d_, pr, SP_, MW, SM, SUZ, SLZ, rxP, k0P, acc, w, \
                    (float*)(obase + vO), guard); \
    vO += G4; \
} while (0)

#define ITERADV(MM) do { ITER(MM, vRun); vRun += G12; } while (0)

#define ITER_NL(MM) do { \
    constexpr int PH_ = (MM) % RLEN; \
    constexpr int S_  = ((MM) + 1) % 5; \
    const F3 f_ = bF[S_], d_ = bD[S_]; \
    fused_iter<PH_>(f_, d_, pr, SP_, MW, SM, SUZ, SLZ, rxP, k0P, acc, w, \
                    (float*)(obase + vO), guard); \
    vO += G4; \
} while (0)

    // ---- main: m = 0..344 (23 x 15); stages rows 6..350 ----
    for (int i = 0; i < 23; ++i) {
        ITERADV(0);  ITERADV(1);  ITERADV(2);  ITERADV(3);  ITERADV(4);
        ITERADV(5);  ITERADV(6);  ITERADV(7);  ITERADV(8);  ITERADV(9);
        ITERADV(10); ITERADV(11); ITERADV(12); ITERADV(13); ITERADV(14);
    }
    // ---- penultimate: m = 345..358 stage rows 351..364; m=359 re-stages 364
    //      (its slot, step 365, is never consumed) ----
    ITERADV(0);  ITERADV(1);  ITERADV(2);  ITERADV(3);  ITERADV(4);
    ITERADV(5);  ITERADV(6);  ITERADV(7);  ITERADV(8);  ITERADV(9);
    ITERADV(10); ITERADV(11); ITERADV(12); ITERADV(13);
    ITER(14, (unsigned)gc * 12u + 364u * G12);     // m = 359
    // ---- epilogue: m = 360..363 consume rows 361..364 (already staged) ----
    ITER_NL(0); ITER_NL(1); ITER_NL(2); ITER_NL(3);
    // ---- final: finish(364), phase 364 % 15 = 4 ----
    finish_step<4>(pr, SUZ, SLZ, rxP, k0P, acc, w, (float*)(obase + vO), guard);
#undef ITER_NL
#undef ITERADV
#undef ITER
}

extern "C" void kernel_launch(void* const* d_in, const int* in_sizes, int n_in,
                              void* d_out, int out_size, void* d_ws, size_t ws_size,
                              hipStream_t stream) {
    const float* forcing = (const float*)d_in[0];
    const float* dynr    = (const float*)d_in[1];
    const float* statr   = (const float*)d_in[2];
    float* out = (float*)d_out;

    const int G = in_sizes[2] / 15;          // static_raw (G,15); T fixed at 365
    const int block = 256;
    const int grid  = (G + block - 1) / block;
    hbv_kernel<<<grid, block, 0, stream>>>(forcing, dynr, statr, out, G);
}